// Round 10
// baseline (577.958 us; speedup 1.0000x reference)
//
#include <hip/hip_runtime.h>

#define O_ 2048
#define M_ 512
#define FIN 64
#define FMAS 64
#define DOUT 32
#define H_ 128
#define TD 96
#define NB_ 3

typedef __attribute__((ext_vector_type(4))) float f32x4;
typedef __attribute__((ext_vector_type(8))) short bf16x8;

__device__ __forceinline__ float elu_f(float x) {
    return x > 0.f ? x : (__expf(x) - 1.f);
}
// round-to-nearest-even f32 -> bf16
__device__ __forceinline__ unsigned short f2b(float x) {
    union { float f; unsigned u; } uu; uu.f = x;
    unsigned r = uu.u + 0x7fffu + ((uu.u >> 16) & 1u);
    return (unsigned short)(r >> 16);
}
__device__ __forceinline__ float b2f(unsigned short s) {
    union { float f; unsigned u; } uu; uu.u = ((unsigned)s) << 16;
    return uu.f;
}
// truncation split: x ~= hi + lo (each bf16)
__device__ __forceinline__ void splitw(float x, short& h, short& lo) {
    unsigned u = __float_as_uint(x);
    unsigned short hi = (unsigned short)(u >> 16);
    float rem = x - b2f(hi);
    h = (short)hi;
    lo = (short)(unsigned short)(__float_as_uint(rem) >> 16);
}

// ---------------------------------------------------------------------------
// K0: scalars k_e, c_e and basis-combined relation weights Wt[f][t*32+e]
// ---------------------------------------------------------------------------
__global__ void k0_setup(const float* __restrict__ e_w1, const float* __restrict__ e_b1,
                         const float* __restrict__ e_w2, const float* __restrict__ e_b2,
                         const float* __restrict__ coeff, const float* __restrict__ v,
                         float* __restrict__ ws_scal, float* __restrict__ ws_wt) {
    __shared__ float r1[128], r2[128];
    const int t = threadIdx.x;
    r1[t] = e_w1[t] * e_w2[t];
    r2[t] = e_b1[t] * e_w2[t];
    __syncthreads();
    for (int s = 64; s > 0; s >>= 1) {
        if (t < s) { r1[t] += r1[t + s]; r2[t] += r2[t + s]; }
        __syncthreads();
    }
    if (t == 0) { ws_scal[0] = r1[0]; ws_scal[1] = r2[0] + e_b2[0]; }
    for (int idx = t; idx < FMAS * TD; idx += 128) {
        int f = idx / TD, te = idx % TD;
        int tt = te / DOUT, e = te % DOUT;
        float s = 0.f;
        for (int nb = 0; nb < NB_; ++nb)
            s += coeff[tt * NB_ + nb] * v[(nb * FMAS + f) * DOUT + e];
        ws_wt[idx] = s;
    }
}

// ---------------------------------------------------------------------------
// KHF: per-li bf16 H fragment tables -> ws  ([4 ft][16 ks][64 lane] bf16x8)
// ---------------------------------------------------------------------------
__global__ __launch_bounds__(256) void khf(const float* __restrict__ hmas,
                                           const int* __restrict__ bidx,
                                           bf16x8* __restrict__ hf) {
    const int t = threadIdx.x;
    const int li = blockIdx.x >> 2;
    const int part = blockIdx.x & 3;
    const int bi = bidx[li];
    const float* hb = hmas + (long long)bi * M_ * FMAS;
    bf16x8* dst = hf + li * 4096;
    #pragma unroll
    for (int j4 = 0; j4 < 4; ++j4) {
        int e = part * 1024 + j4 * 256 + t;
        int ft = e >> 10, ks = (e >> 6) & 15, le = e & 63;
        int cc = le & 15, gg = le >> 4;
        const float* src = hb + (ks * 32 + gg * 8) * FMAS + ft * 16 + cc;
        bf16x8 vv;
        #pragma unroll
        for (int j = 0; j < 8; ++j) vv[j] = (short)f2b(src[j * FMAS]);
        dst[e] = vv;
    }
}

// ---------------------------------------------------------------------------
// G2 v2 (DIAGNOSTIC x3): agg = (mask*(ke*feat2+ce)) @ H, LDS-staged A-tile.
// Body repeated 3x (accumulate, scale 1/3 at store) to push this dispatch
// above the harness fill kernels' ~150us so it appears in top-5 counters.
// asm memory clobber between reps prevents load CSE; MFMAs stay live.
// ---------------------------------------------------------------------------
__global__ __launch_bounds__(256, 3) void g2(
        const float* __restrict__ feat2, const int* __restrict__ adj,
        const int* __restrict__ bidx, const float* __restrict__ scal,
        const bf16x8* __restrict__ hf, float* __restrict__ agg) {
    __shared__ char tile[32768];              // 8 KB per wave (feat2 4K + adj 4K)
    const int t = threadIdx.x;
    const int w = t >> 6, l = t & 63;
    const int c = l & 15, g = l >> 4;
    const int r16 = blockIdx.x * 4 + w;       // 16-row unit id
    const int li = r16 >> 7;
    const int bi = bidx[li];
    float ke = scal[0], ce = scal[1];
    asm volatile("" : "+v"(ke), "+v"(ce));    // VGPR-pin (constant-bus limit)
    const long long rowg = (long long)bi * O_ + ((r16 & 127) * 16);
    const float* f2base = feat2 + rowg * M_;
    const int*   adb    = adj   + rowg * M_;
    const bf16x8* hfb = hf + li * 4096;
    char* wbase = tile + w * 8192;

    const int rl = l >> 4, q = l & 15;
    const float* gF0 = f2base + (0 * 4 + rl) * 512 + q * 4;
    const float* gF1 = f2base + (1 * 4 + rl) * 512 + q * 4;
    const float* gF2 = f2base + (2 * 4 + rl) * 512 + q * 4;
    const float* gF3 = f2base + (3 * 4 + rl) * 512 + q * 4;
    const int* gA0 = adb + (0 * 4 + rl) * 512 + q * 4;
    const int* gA1 = adb + (1 * 4 + rl) * 512 + q * 4;
    const int* gA2 = adb + (2 * 4 + rl) * 512 + q * 4;
    const int* gA3 = adb + (3 * 4 + rl) * 512 + q * 4;
    char* wp0 = wbase + (((0 * 4 + rl) * 16 + (q ^ ((0 * 4 + rl) & 7))) * 16);
    char* wp1 = wbase + (((1 * 4 + rl) * 16 + (q ^ ((1 * 4 + rl) & 7))) * 16);
    char* wp2 = wbase + (((2 * 4 + rl) * 16 + (q ^ ((2 * 4 + rl) & 7))) * 16);
    char* wp3 = wbase + (((3 * 4 + rl) * 16 + (q ^ ((3 * 4 + rl) & 7))) * 16);
    const int s7 = c & 7;
    const char* rd0 = wbase + ((c * 16 + ((g * 2 + 0) ^ s7)) * 16);
    const char* rd1 = wbase + ((c * 16 + ((g * 2 + 1) ^ s7)) * 16);

    f32x4 acc0 = {0.f, 0.f, 0.f, 0.f}, acc1 = {0.f, 0.f, 0.f, 0.f};
    f32x4 acc2 = {0.f, 0.f, 0.f, 0.f}, acc3 = {0.f, 0.f, 0.f, 0.f};

    float4 f0, f1, f2, f3, nf0, nf1, nf2, nf3;
    int4   a0, a1, a2, a3, na0, na1, na2, na3;

#define G2LOADG(ch, F0, F1, F2, F3, A0, A1, A2, A3) {                   \
    F0 = *(const float4*)(gF0 + (ch) * 64);                             \
    F1 = *(const float4*)(gF1 + (ch) * 64);                             \
    F2 = *(const float4*)(gF2 + (ch) * 64);                             \
    F3 = *(const float4*)(gF3 + (ch) * 64);                             \
    A0 = *(const int4*)(gA0 + (ch) * 64);                               \
    A1 = *(const int4*)(gA1 + (ch) * 64);                               \
    A2 = *(const int4*)(gA2 + (ch) * 64);                               \
    A3 = *(const int4*)(gA3 + (ch) * 64); }

#define G2STORE_LDS() {                                                 \
    *(float4*)wp0 = f0; *(float4*)wp1 = f1;                             \
    *(float4*)wp2 = f2; *(float4*)wp3 = f3;                             \
    *(int4*)(wp0 + 4096) = a0; *(int4*)(wp1 + 4096) = a1;               \
    *(int4*)(wp2 + 4096) = a2; *(int4*)(wp3 + 4096) = a3; }

#define G2CV4(e4, m4, ah, al_, o) {                                     \
    short h_, l_;                                                       \
    splitw((m4.x == 1) ? fmaf(e4.x, ke, ce) : 0.f, h_, l_);             \
    ah[o + 0] = h_; al_[o + 0] = l_;                                    \
    splitw((m4.y == 1) ? fmaf(e4.y, ke, ce) : 0.f, h_, l_);             \
    ah[o + 1] = h_; al_[o + 1] = l_;                                    \
    splitw((m4.z == 1) ? fmaf(e4.z, ke, ce) : 0.f, h_, l_);             \
    ah[o + 2] = h_; al_[o + 2] = l_;                                    \
    splitw((m4.w == 1) ? fmaf(e4.w, ke, ce) : 0.f, h_, l_);             \
    ah[o + 3] = h_; al_[o + 3] = l_; }

#define G2KS(ksg, off) {                                                \
    float4 e0 = *(const float4*)(rd0 + (off));                          \
    float4 e1 = *(const float4*)(rd1 + (off));                          \
    int4   m0 = *(const int4*)(rd0 + 4096 + (off));                     \
    int4   m1 = *(const int4*)(rd1 + 4096 + (off));                     \
    bf16x8 bb0 = hfb[(0 * 16 + (ksg)) * 64 + l];                        \
    bf16x8 bb1 = hfb[(1 * 16 + (ksg)) * 64 + l];                        \
    bf16x8 bb2 = hfb[(2 * 16 + (ksg)) * 64 + l];                        \
    bf16x8 bb3 = hfb[(3 * 16 + (ksg)) * 64 + l];                        \
    bf16x8 ah, al_;                                                     \
    G2CV4(e0, m0, ah, al_, 0);                                          \
    G2CV4(e1, m1, ah, al_, 4);                                          \
    acc0 = __builtin_amdgcn_mfma_f32_16x16x32_bf16(ah, bb0, acc0, 0, 0, 0); \
    acc0 = __builtin_amdgcn_mfma_f32_16x16x32_bf16(al_, bb0, acc0, 0, 0, 0); \
    acc1 = __builtin_amdgcn_mfma_f32_16x16x32_bf16(ah, bb1, acc1, 0, 0, 0); \
    acc1 = __builtin_amdgcn_mfma_f32_16x16x32_bf16(al_, bb1, acc1, 0, 0, 0); \
    acc2 = __builtin_amdgcn_mfma_f32_16x16x32_bf16(ah, bb2, acc2, 0, 0, 0); \
    acc2 = __builtin_amdgcn_mfma_f32_16x16x32_bf16(al_, bb2, acc2, 0, 0, 0); \
    acc3 = __builtin_amdgcn_mfma_f32_16x16x32_bf16(ah, bb3, acc3, 0, 0, 0); \
    acc3 = __builtin_amdgcn_mfma_f32_16x16x32_bf16(al_, bb3, acc3, 0, 0, 0); }

    // DIAGNOSTIC: 3x repeat (accumulate; scale 1/3 at store)
    #pragma unroll 1
    for (int rep = 0; rep < 3; ++rep) {
        asm volatile("" ::: "memory");
        G2LOADG(0, f0, f1, f2, f3, a0, a1, a2, a3);
        #pragma unroll
        for (int ch = 0; ch < 8; ++ch) {
            G2STORE_LDS();
            if (ch < 7) G2LOADG(ch + 1, nf0, nf1, nf2, nf3, na0, na1, na2, na3);
            G2KS(ch * 2 + 0, 0);
            G2KS(ch * 2 + 1, 128);
            f0 = nf0; f1 = nf1; f2 = nf2; f3 = nf3;
            a0 = na0; a1 = na1; a2 = na2; a3 = na3;
        }
    }

    const float s3 = 1.0f / 3.0f;
    const long long rb = (long long)r16 * 16;
    #pragma unroll
    for (int reg = 0; reg < 4; ++reg) {
        long long row = rb + g * 4 + reg;
        agg[row * 64 +  0 + c] = acc0[reg] * s3;
        agg[row * 64 + 16 + c] = acc1[reg] * s3;
        agg[row * 64 + 32 + c] = acc2[reg] * s3;
        agg[row * 64 + 48 + c] = acc3[reg] * s3;
    }
#undef G2LOADG
#undef G2STORE_LDS
#undef G2CV4
#undef G2KS
}

// ---------------------------------------------------------------------------
// G134 (DIAGNOSTIC x12): G1 + G3 + G4 + epilogue, body repeated 12x.
// Stores re-execute each rep (identical values) so nothing is DCE'd; extra
// barrier at loop end removes the benign re-staging race.
// ---------------------------------------------------------------------------
__global__ __launch_bounds__(256) void g134(
        const float* __restrict__ feat0, const int* __restrict__ bidx,
        const float* __restrict__ aggws, const float* __restrict__ wt,
        const float* __restrict__ w0w1, const float* __restrict__ w0b1,
        const float* __restrict__ w0w2, const float* __restrict__ w0b2,
        const float* __restrict__ om1, const float* __restrict__ omb1,
        const float* __restrict__ om2v, const float* __restrict__ omb2,
        float* __restrict__ out) {
    __shared__ __align__(16) char poolW[98304];
    __shared__ __align__(16) char poolS[45056];
    __shared__ float sB1w0[128], sB2w0[32], sB1om[128], sOm2[128];

    const int t = threadIdx.x;
    const int l = t & 63, w = t >> 6;
    const int c = l & 15, g = l >> 4;
    const int tile = blockIdx.x;
    const int li = tile >> 4;
    const int o0 = (tile & 15) * 128;
    const int bi = bidx[li];

    bf16x8* sW1f = (bf16x8*)poolW;             // [8 nf][2 ks][64]
    bf16x8* sW2f = (bf16x8*)(poolW + 16384);   // [2 nf][4 ks][64]
    bf16x8* sWtH = (bf16x8*)(poolW + 24576);   // [6 nf][2 ks][64]
    bf16x8* sWtL = (bf16x8*)(poolW + 36864);
    bf16x8* sO1H = (bf16x8*)(poolW + 49152);   // [8 nf][3 ks][64]
    bf16x8* sO1L = (bf16x8*)(poolW + 73728);

    #pragma unroll 1
    for (int rep = 0; rep < 12; ++rep) {
    asm volatile("" ::: "memory");
    if (t < 128) { sB1w0[t] = w0b1[t]; sB1om[t] = omb1[t]; sOm2[t] = om2v[t]; }
    if (t < 32) sB2w0[t] = w0b2[t];

    for (int e = t; e < 1024; e += 256) {
        int nf = e >> 7, ks = (e >> 6) & 1, le = e & 63;
        int cc = le & 15, gg = le >> 4;
        bf16x8 vv;
        #pragma unroll
        for (int j = 0; j < 8; ++j)
            vv[j] = (short)f2b(w0w1[(ks * 32 + gg * 8 + j) * H_ + nf * 16 + cc]);
        sW1f[e] = vv;
    }
    for (int e = t; e < 512; e += 256) {
        int nf = e >> 8, ks = (e >> 6) & 3, le = e & 63;
        int cc = le & 15, gg = le >> 4;
        bf16x8 vv;
        #pragma unroll
        for (int j = 0; j < 8; ++j)
            vv[j] = (short)f2b(w0w2[(ks * 32 + gg * 8 + j) * DOUT + nf * 16 + cc]);
        sW2f[e] = vv;
    }
    for (int e = t; e < 768; e += 256) {
        int nf = e >> 7, ks = (e >> 6) & 1, le = e & 63;
        int cc = le & 15, gg = le >> 4;
        bf16x8 vh, vl;
        #pragma unroll
        for (int j = 0; j < 8; ++j) {
            float vv = wt[(ks * 32 + gg * 8 + j) * TD + nf * 16 + cc];
            short h, lo; splitw(vv, h, lo);
            vh[j] = h; vl[j] = lo;
        }
        sWtH[e] = vh; sWtL[e] = vl;
    }
    for (int e = t; e < 1536; e += 256) {
        int nf = e / 192, r = e % 192, ks = r >> 6, le = r & 63;
        int cc = le & 15, gg = le >> 4;
        bf16x8 vh, vl;
        #pragma unroll
        for (int j = 0; j < 8; ++j) {
            float vv = om1[(ks * 32 + gg * 8 + j) * H_ + nf * 16 + cc];
            short h, lo; splitw(vv, h, lo);
            vh[j] = h; vl[j] = lo;
        }
        sO1H[e] = vh; sO1L[e] = vl;
    }
    __syncthreads();

    // ---- G1 ----
    const float* f0b = feat0 + ((long long)bi * O_ + o0) * FIN;
    char* Sw = poolS + w * 11264;
    f32x4 fo[2][2];
    {
        f32x4 acc1[2][8];
        #pragma unroll
        for (int rf = 0; rf < 2; ++rf)
            #pragma unroll
            for (int nf = 0; nf < 8; ++nf) acc1[rf][nf] = (f32x4){0.f, 0.f, 0.f, 0.f};
        #pragma unroll
        for (int rf = 0; rf < 2; ++rf) {
            #pragma unroll
            for (int ks = 0; ks < 2; ++ks) {
                const float* ap = f0b + (w * 32 + rf * 16 + c) * FIN + ks * 32 + g * 8;
                float4 x0 = *(const float4*)ap;
                float4 x1 = *(const float4*)(ap + 4);
                bf16x8 a;
                a[0] = (short)f2b(x0.x); a[1] = (short)f2b(x0.y);
                a[2] = (short)f2b(x0.z); a[3] = (short)f2b(x0.w);
                a[4] = (short)f2b(x1.x); a[5] = (short)f2b(x1.y);
                a[6] = (short)f2b(x1.z); a[7] = (short)f2b(x1.w);
                #pragma unroll
                for (int nf = 0; nf < 8; ++nf)
                    acc1[rf][nf] = __builtin_amdgcn_mfma_f32_16x16x32_bf16(
                        a, sW1f[(nf * 2 + ks) * 64 + l], acc1[rf][nf], 0, 0, 0);
            }
        }
        #pragma unroll
        for (int rf = 0; rf < 2; ++rf)
            #pragma unroll
            for (int nf = 0; nf < 8; ++nf)
                #pragma unroll
                for (int reg = 0; reg < 4; ++reg) {
                    int row = rf * 16 + g * 4 + reg;
                    float hv = acc1[rf][nf][reg] + sB1w0[nf * 16 + c];
                    *(unsigned short*)(Sw + row * 272 + (nf * 16 + c) * 2) =
                        f2b(elu_f(hv));
                }
        #pragma unroll
        for (int rf = 0; rf < 2; ++rf)
            #pragma unroll
            for (int nf2 = 0; nf2 < 2; ++nf2) fo[rf][nf2] = (f32x4){0.f, 0.f, 0.f, 0.f};
        #pragma unroll
        for (int rf = 0; rf < 2; ++rf)
            #pragma unroll
            for (int ks = 0; ks < 4; ++ks) {
                bf16x8 a = *(const bf16x8*)(Sw + (rf * 16 + c) * 272 + ks * 64 + g * 16);
                #pragma unroll
                for (int nf2 = 0; nf2 < 2; ++nf2)
                    fo[rf][nf2] = __builtin_amdgcn_mfma_f32_16x16x32_bf16(
                        a, sW2f[(nf2 * 4 + ks) * 64 + l], fo[rf][nf2], 0, 0, 0);
            }
    }

    // ---- G3/G4 + epilogue ----
    char* Sw2 = poolS + w * 11264;
    char* tyH = Sw2 + 4608;      // [16][208B]
    char* tyL = Sw2 + 7936;
    const float ob2 = omb2[0];
    const long long aggbase = (long long)tile * 128 + w * 32;
    const long long orow0 = (long long)li * O_ + o0 + w * 32;

    #pragma unroll
    for (int rf = 0; rf < 2; ++rf) {
        f32x4 ty[6];
        #pragma unroll
        for (int nf = 0; nf < 6; ++nf) ty[nf] = (f32x4){0.f, 0.f, 0.f, 0.f};
        #pragma unroll
        for (int ks = 0; ks < 2; ++ks) {
            const float* ag = aggws + (aggbase + rf * 16 + c) * 64 + ks * 32 + g * 8;
            float4 x0 = *(const float4*)ag;
            float4 x1 = *(const float4*)(ag + 4);
            bf16x8 aH, aL;
            short h, lo;
            splitw(x0.x, h, lo); aH[0] = h; aL[0] = lo;
            splitw(x0.y, h, lo); aH[1] = h; aL[1] = lo;
            splitw(x0.z, h, lo); aH[2] = h; aL[2] = lo;
            splitw(x0.w, h, lo); aH[3] = h; aL[3] = lo;
            splitw(x1.x, h, lo); aH[4] = h; aL[4] = lo;
            splitw(x1.y, h, lo); aH[5] = h; aL[5] = lo;
            splitw(x1.z, h, lo); aH[6] = h; aL[6] = lo;
            splitw(x1.w, h, lo); aH[7] = h; aL[7] = lo;
            #pragma unroll
            for (int nf = 0; nf < 6; ++nf) {
                bf16x8 bH = sWtH[(nf * 2 + ks) * 64 + l];
                bf16x8 bL = sWtL[(nf * 2 + ks) * 64 + l];
                ty[nf] = __builtin_amdgcn_mfma_f32_16x16x32_bf16(aH, bH, ty[nf], 0, 0, 0);
                ty[nf] = __builtin_amdgcn_mfma_f32_16x16x32_bf16(aL, bH, ty[nf], 0, 0, 0);
                ty[nf] = __builtin_amdgcn_mfma_f32_16x16x32_bf16(aH, bL, ty[nf], 0, 0, 0);
            }
        }
        #pragma unroll
        for (int nf = 0; nf < 6; ++nf)
            #pragma unroll
            for (int reg = 0; reg < 4; ++reg) {
                int row = g * 4 + reg;
                float vv = ty[nf][reg];
                short h, lo; splitw(vv, h, lo);
                *(short*)(tyH + row * 208 + (nf * 16 + c) * 2) = h;
                *(short*)(tyL + row * 208 + (nf * 16 + c) * 2) = lo;
            }
        f32x4 h2[8];
        #pragma unroll
        for (int nf = 0; nf < 8; ++nf) h2[nf] = (f32x4){0.f, 0.f, 0.f, 0.f};
        #pragma unroll
        for (int ks = 0; ks < 3; ++ks) {
            bf16x8 aH = *(const bf16x8*)(tyH + c * 208 + ks * 64 + g * 16);
            bf16x8 aL = *(const bf16x8*)(tyL + c * 208 + ks * 64 + g * 16);
            #pragma unroll
            for (int nf = 0; nf < 8; ++nf) {
                bf16x8 bH = sO1H[(nf * 3 + ks) * 64 + l];
                bf16x8 bL = sO1L[(nf * 3 + ks) * 64 + l];
                h2[nf] = __builtin_amdgcn_mfma_f32_16x16x32_bf16(aH, bH, h2[nf], 0, 0, 0);
                h2[nf] = __builtin_amdgcn_mfma_f32_16x16x32_bf16(aL, bH, h2[nf], 0, 0, 0);
                h2[nf] = __builtin_amdgcn_mfma_f32_16x16x32_bf16(aH, bL, h2[nf], 0, 0, 0);
            }
        }
        float p[4] = {0.f, 0.f, 0.f, 0.f};
        #pragma unroll
        for (int nf = 0; nf < 8; ++nf) {
            float o2 = sOm2[nf * 16 + c];
            float bb = sB1om[nf * 16 + c];
            #pragma unroll
            for (int reg = 0; reg < 4; ++reg)
                p[reg] += elu_f(h2[nf][reg] + bb) * o2;
        }
        #pragma unroll
        for (int reg = 0; reg < 4; ++reg) {
            #pragma unroll
            for (int off = 1; off < 16; off <<= 1)
                p[reg] += __shfl_xor(p[reg], off, 64);
            p[reg] += ob2;
        }
        #pragma unroll
        for (int nf2 = 0; nf2 < 2; ++nf2) {
            float b2v = sB2w0[nf2 * 16 + c];
            #pragma unroll
            for (int reg = 0; reg < 4; ++reg) {
                long long orow = orow0 + rf * 16 + g * 4 + reg;
                float val = fo[rf][nf2][reg] + b2v + p[reg];
                val = val >= 0.f ? val : 0.2f * val;
                out[orow * DOUT + nf2 * 16 + c] = val;
            }
        }
    }
    __syncthreads();   // end-of-rep barrier (no re-staging race)
    }
}

// ---------------------------------------------------------------------------
extern "C" void kernel_launch(void* const* d_in, const int* in_sizes, int n_in,
                              void* d_out, int out_size, void* d_ws, size_t ws_size,
                              hipStream_t stream) {
    const float* feat0 = (const float*)d_in[0];
    const float* feat1 = (const float*)d_in[1];
    const float* feat2 = (const float*)d_in[2];
    const int*   adj   = (const int*)d_in[3];
    const int*   bidx  = (const int*)d_in[4];
    const float* w0_w1 = (const float*)d_in[5];
    const float* w0_b1 = (const float*)d_in[6];
    const float* w0_w2 = (const float*)d_in[7];
    const float* w0_b2 = (const float*)d_in[8];
    const float* v     = (const float*)d_in[9];
    const float* coeff = (const float*)d_in[10];
    const float* e_w1  = (const float*)d_in[11];
    const float* e_b1  = (const float*)d_in[12];
    const float* e_w2  = (const float*)d_in[13];
    const float* e_b2  = (const float*)d_in[14];
    const float* om_w1 = (const float*)d_in[15];
    const float* om_b1 = (const float*)d_in[16];
    const float* om_w2 = (const float*)d_in[17];
    const float* om_b2 = (const float*)d_in[18];
    float* out = (float*)d_out;
    float* ws  = (float*)d_ws;

    const int bsel = in_sizes[4];              // 32
    float*  ws_scal = ws;                      // 16 floats
    float*  ws_wt   = ws + 16;                 // 6144 floats
    bf16x8* ws_hf   = (bf16x8*)((char*)ws + 32768);          // 2 MB
    float*  ws_agg  = (float*)((char*)ws + 32768 + 2097152); // 16.8 MB

    k0_setup<<<1, 128, 0, stream>>>(e_w1, e_b1, e_w2, e_b2, coeff, v, ws_scal, ws_wt);
    khf<<<bsel * 4, 256, 0, stream>>>(feat1, bidx, ws_hf);
    g2<<<bsel * 32, 256, 0, stream>>>(feat2, adj, bidx, ws_scal, ws_hf, ws_agg);
    g134<<<bsel * 16, 256, 0, stream>>>(feat0, bidx, ws_agg, ws_wt,
                                        w0_w1, w0_b1, w0_w2, w0_b2,
                                        om_w1, om_b1, om_w2, om_b2, out);
}

// Round 11
// 89.209 us; speedup vs baseline: 6.4787x; 6.4787x over previous
//
#include <hip/hip_runtime.h>

#define O_ 2048
#define M_ 512
#define FIN 64
#define FMAS 64
#define DOUT 32
#define H_ 128
#define TD 96
#define NB_ 3

typedef __attribute__((ext_vector_type(4))) float f32x4;
typedef __attribute__((ext_vector_type(8))) short bf16x8;

__device__ __forceinline__ float elu_f(float x) {
    return x > 0.f ? x : (__expf(x) - 1.f);
}
// round-to-nearest-even f32 -> bf16
__device__ __forceinline__ unsigned short f2b(float x) {
    union { float f; unsigned u; } uu; uu.f = x;
    unsigned r = uu.u + 0x7fffu + ((uu.u >> 16) & 1u);
    return (unsigned short)(r >> 16);
}
__device__ __forceinline__ float b2f(unsigned short s) {
    union { float f; unsigned u; } uu; uu.u = ((unsigned)s) << 16;
    return uu.f;
}
// truncation split: x ~= hi + lo (each bf16)
__device__ __forceinline__ void splitw(float x, short& h, short& lo) {
    unsigned u = __float_as_uint(x);
    unsigned short hi = (unsigned short)(u >> 16);
    float rem = x - b2f(hi);
    h = (short)hi;
    lo = (short)(unsigned short)(__float_as_uint(rem) >> 16);
}

// ---------------------------------------------------------------------------
// KPREP (15 blocks x 256): scalars k_e/c_e + ALL weight fragment tables -> ws.
// Entry e in [0,3840): [0,1024) W1f | [1024,1536) W2f | [1536,2304) Wt hi/lo
// (computed directly from coeff x v) | [2304,3840) om1 hi/lo.
// Replaces per-block LDS weight staging in g134 (was 96 KB LDS + ~4K VALU
// per block -> 1 block/CU, 1 wave/SIMD, the R10-measured occupancy killer).
// ---------------------------------------------------------------------------
__global__ __launch_bounds__(256) void kprep(
        const float* __restrict__ e_w1, const float* __restrict__ e_b1,
        const float* __restrict__ e_w2, const float* __restrict__ e_b2,
        const float* __restrict__ coeff, const float* __restrict__ v,
        const float* __restrict__ w0w1, const float* __restrict__ w0w2,
        const float* __restrict__ om1,
        float* __restrict__ ws_scal,
        bf16x8* __restrict__ w1f, bf16x8* __restrict__ w2f,
        bf16x8* __restrict__ wth, bf16x8* __restrict__ wtl,
        bf16x8* __restrict__ o1h, bf16x8* __restrict__ o1l) {
    __shared__ float r1[128], r2[128];
    const int t = threadIdx.x;
    if (t < 128) { r1[t] = e_w1[t] * e_w2[t]; r2[t] = e_b1[t] * e_w2[t]; }
    __syncthreads();
    for (int s = 64; s > 0; s >>= 1) {
        if (t < s) { r1[t] += r1[t + s]; r2[t] += r2[t + s]; }
        __syncthreads();
    }
    if (blockIdx.x == 0 && t == 0) {
        ws_scal[0] = r1[0];
        ws_scal[1] = r2[0] + e_b2[0];
    }
    const int e = blockIdx.x * 256 + t;       // [0, 3840)
    const int le = e & 63, cc = le & 15, gg = le >> 4;
    if (e < 1024) {
        int nf = e >> 7, ks = (e >> 6) & 1;
        bf16x8 vv;
        #pragma unroll
        for (int j = 0; j < 8; ++j)
            vv[j] = (short)f2b(w0w1[(ks * 32 + gg * 8 + j) * H_ + nf * 16 + cc]);
        w1f[e] = vv;
    } else if (e < 1536) {
        int e2 = e - 1024;
        int nf = e2 >> 8, ks = (e2 >> 6) & 3;
        bf16x8 vv;
        #pragma unroll
        for (int j = 0; j < 8; ++j)
            vv[j] = (short)f2b(w0w2[(ks * 32 + gg * 8 + j) * DOUT + nf * 16 + cc]);
        w2f[e2] = vv;
    } else if (e < 2304) {
        int e3 = e - 1536;
        int nf = e3 >> 7, ks = (e3 >> 6) & 1;
        bf16x8 vh, vl;
        #pragma unroll
        for (int j = 0; j < 8; ++j) {
            int row = ks * 32 + gg * 8 + j;    // f index
            int col = nf * 16 + cc;            // t*32+e index
            int tt = col >> 5, ee = col & 31;
            float s = 0.f;
            #pragma unroll
            for (int nb = 0; nb < NB_; ++nb)
                s += coeff[tt * NB_ + nb] * v[(nb * FMAS + row) * DOUT + ee];
            short h, lo; splitw(s, h, lo);
            vh[j] = h; vl[j] = lo;
        }
        wth[e3] = vh; wtl[e3] = vl;
    } else if (e < 3840) {
        int e4 = e - 2304;
        int nf = e4 / 192, r = e4 % 192, ks = r >> 6;
        bf16x8 vh, vl;
        #pragma unroll
        for (int j = 0; j < 8; ++j) {
            float vv = om1[(ks * 32 + gg * 8 + j) * H_ + nf * 16 + cc];
            short h, lo; splitw(vv, h, lo);
            vh[j] = h; vl[j] = lo;
        }
        o1h[e4] = vh; o1l[e4] = vl;
    }
}

// ---------------------------------------------------------------------------
// KHF: per-li bf16 H fragment tables -> ws  ([4 ft][16 ks][64 lane] bf16x8)
// ---------------------------------------------------------------------------
__global__ __launch_bounds__(256) void khf(const float* __restrict__ hmas,
                                           const int* __restrict__ bidx,
                                           bf16x8* __restrict__ hf) {
    const int t = threadIdx.x;
    const int li = blockIdx.x >> 2;
    const int part = blockIdx.x & 3;
    const int bi = bidx[li];
    const float* hb = hmas + (long long)bi * M_ * FMAS;
    bf16x8* dst = hf + li * 4096;
    #pragma unroll
    for (int j4 = 0; j4 < 4; ++j4) {
        int e = part * 1024 + j4 * 256 + t;
        int ft = e >> 10, ks = (e >> 6) & 15, le = e & 63;
        int cc = le & 15, gg = le >> 4;
        const float* src = hb + (ks * 32 + gg * 8) * FMAS + ft * 16 + cc;
        bf16x8 vv;
        #pragma unroll
        for (int j = 0; j < 8; ++j) vv[j] = (short)f2b(src[j * FMAS]);
        dst[e] = vv;
    }
}

// ---------------------------------------------------------------------------
// G2 (R9 structure, diagnostics reverted): agg = (mask*(ke*feat2+ce)) @ H.
// LDS-staged A-tile, per-wave 16 rows, no barriers; XOR-swizzled LDS;
// B-frags from L2-hot ws table.
// ---------------------------------------------------------------------------
__global__ __launch_bounds__(256, 3) void g2(
        const float* __restrict__ feat2, const int* __restrict__ adj,
        const int* __restrict__ bidx, const float* __restrict__ scal,
        const bf16x8* __restrict__ hf, float* __restrict__ agg) {
    __shared__ char tile[32768];              // 8 KB per wave (feat2 4K + adj 4K)
    const int t = threadIdx.x;
    const int w = t >> 6, l = t & 63;
    const int c = l & 15, g = l >> 4;
    const int r16 = blockIdx.x * 4 + w;       // 16-row unit id
    const int li = r16 >> 7;
    const int bi = bidx[li];
    float ke = scal[0], ce = scal[1];
    asm volatile("" : "+v"(ke), "+v"(ce));    // VGPR-pin (constant-bus limit)
    const long long rowg = (long long)bi * O_ + ((r16 & 127) * 16);
    const float* f2base = feat2 + rowg * M_;
    const int*   adb    = adj   + rowg * M_;
    const bf16x8* hfb = hf + li * 4096;
    char* wbase = tile + w * 8192;

    const int rl = l >> 4, q = l & 15;
    const float* gF0 = f2base + (0 * 4 + rl) * 512 + q * 4;
    const float* gF1 = f2base + (1 * 4 + rl) * 512 + q * 4;
    const float* gF2 = f2base + (2 * 4 + rl) * 512 + q * 4;
    const float* gF3 = f2base + (3 * 4 + rl) * 512 + q * 4;
    const int* gA0 = adb + (0 * 4 + rl) * 512 + q * 4;
    const int* gA1 = adb + (1 * 4 + rl) * 512 + q * 4;
    const int* gA2 = adb + (2 * 4 + rl) * 512 + q * 4;
    const int* gA3 = adb + (3 * 4 + rl) * 512 + q * 4;
    char* wp0 = wbase + (((0 * 4 + rl) * 16 + (q ^ ((0 * 4 + rl) & 7))) * 16);
    char* wp1 = wbase + (((1 * 4 + rl) * 16 + (q ^ ((1 * 4 + rl) & 7))) * 16);
    char* wp2 = wbase + (((2 * 4 + rl) * 16 + (q ^ ((2 * 4 + rl) & 7))) * 16);
    char* wp3 = wbase + (((3 * 4 + rl) * 16 + (q ^ ((3 * 4 + rl) & 7))) * 16);
    const int s7 = c & 7;
    const char* rd0 = wbase + ((c * 16 + ((g * 2 + 0) ^ s7)) * 16);
    const char* rd1 = wbase + ((c * 16 + ((g * 2 + 1) ^ s7)) * 16);

    f32x4 acc0 = {0.f, 0.f, 0.f, 0.f}, acc1 = {0.f, 0.f, 0.f, 0.f};
    f32x4 acc2 = {0.f, 0.f, 0.f, 0.f}, acc3 = {0.f, 0.f, 0.f, 0.f};

    float4 f0, f1, f2, f3, nf0, nf1, nf2, nf3;
    int4   a0, a1, a2, a3, na0, na1, na2, na3;

#define G2LOADG(ch, F0, F1, F2, F3, A0, A1, A2, A3) {                   \
    F0 = *(const float4*)(gF0 + (ch) * 64);                             \
    F1 = *(const float4*)(gF1 + (ch) * 64);                             \
    F2 = *(const float4*)(gF2 + (ch) * 64);                             \
    F3 = *(const float4*)(gF3 + (ch) * 64);                             \
    A0 = *(const int4*)(gA0 + (ch) * 64);                               \
    A1 = *(const int4*)(gA1 + (ch) * 64);                               \
    A2 = *(const int4*)(gA2 + (ch) * 64);                               \
    A3 = *(const int4*)(gA3 + (ch) * 64); }

#define G2STORE_LDS() {                                                 \
    *(float4*)wp0 = f0; *(float4*)wp1 = f1;                             \
    *(float4*)wp2 = f2; *(float4*)wp3 = f3;                             \
    *(int4*)(wp0 + 4096) = a0; *(int4*)(wp1 + 4096) = a1;               \
    *(int4*)(wp2 + 4096) = a2; *(int4*)(wp3 + 4096) = a3; }

#define G2CV4(e4, m4, ah, al_, o) {                                     \
    short h_, l_;                                                       \
    splitw((m4.x == 1) ? fmaf(e4.x, ke, ce) : 0.f, h_, l_);             \
    ah[o + 0] = h_; al_[o + 0] = l_;                                    \
    splitw((m4.y == 1) ? fmaf(e4.y, ke, ce) : 0.f, h_, l_);             \
    ah[o + 1] = h_; al_[o + 1] = l_;                                    \
    splitw((m4.z == 1) ? fmaf(e4.z, ke, ce) : 0.f, h_, l_);             \
    ah[o + 2] = h_; al_[o + 2] = l_;                                    \
    splitw((m4.w == 1) ? fmaf(e4.w, ke, ce) : 0.f, h_, l_);             \
    ah[o + 3] = h_; al_[o + 3] = l_; }

#define G2KS(ksg, off) {                                                \
    float4 e0 = *(const float4*)(rd0 + (off));                          \
    float4 e1 = *(const float4*)(rd1 + (off));                          \
    int4   m0 = *(const int4*)(rd0 + 4096 + (off));                     \
    int4   m1 = *(const int4*)(rd1 + 4096 + (off));                     \
    bf16x8 bb0 = hfb[(0 * 16 + (ksg)) * 64 + l];                        \
    bf16x8 bb1 = hfb[(1 * 16 + (ksg)) * 64 + l];                        \
    bf16x8 bb2 = hfb[(2 * 16 + (ksg)) * 64 + l];                        \
    bf16x8 bb3 = hfb[(3 * 16 + (ksg)) * 64 + l];                        \
    bf16x8 ah, al_;                                                     \
    G2CV4(e0, m0, ah, al_, 0);                                          \
    G2CV4(e1, m1, ah, al_, 4);                                          \
    acc0 = __builtin_amdgcn_mfma_f32_16x16x32_bf16(ah, bb0, acc0, 0, 0, 0); \
    acc0 = __builtin_amdgcn_mfma_f32_16x16x32_bf16(al_, bb0, acc0, 0, 0, 0); \
    acc1 = __builtin_amdgcn_mfma_f32_16x16x32_bf16(ah, bb1, acc1, 0, 0, 0); \
    acc1 = __builtin_amdgcn_mfma_f32_16x16x32_bf16(al_, bb1, acc1, 0, 0, 0); \
    acc2 = __builtin_amdgcn_mfma_f32_16x16x32_bf16(ah, bb2, acc2, 0, 0, 0); \
    acc2 = __builtin_amdgcn_mfma_f32_16x16x32_bf16(al_, bb2, acc2, 0, 0, 0); \
    acc3 = __builtin_amdgcn_mfma_f32_16x16x32_bf16(ah, bb3, acc3, 0, 0, 0); \
    acc3 = __builtin_amdgcn_mfma_f32_16x16x32_bf16(al_, bb3, acc3, 0, 0, 0); }

    G2LOADG(0, f0, f1, f2, f3, a0, a1, a2, a3);
    #pragma unroll
    for (int ch = 0; ch < 8; ++ch) {
        G2STORE_LDS();
        if (ch < 7) G2LOADG(ch + 1, nf0, nf1, nf2, nf3, na0, na1, na2, na3);
        G2KS(ch * 2 + 0, 0);
        G2KS(ch * 2 + 1, 128);
        f0 = nf0; f1 = nf1; f2 = nf2; f3 = nf3;
        a0 = na0; a1 = na1; a2 = na2; a3 = na3;
    }

    const long long rb = (long long)r16 * 16;
    #pragma unroll
    for (int reg = 0; reg < 4; ++reg) {
        long long row = rb + g * 4 + reg;
        agg[row * 64 +  0 + c] = acc0[reg];
        agg[row * 64 + 16 + c] = acc1[reg];
        agg[row * 64 + 32 + c] = acc2[reg];
        agg[row * 64 + 48 + c] = acc3[reg];
    }
#undef G2LOADG
#undef G2STORE_LDS
#undef G2CV4
#undef G2KS
}

// ---------------------------------------------------------------------------
// G134 v2: G1 + G3 + G4 + epilogue. Weight fragments read from L2-hot ws
// tables (no weight LDS, no staging loops). LDS = per-wave scratch + biases
// (~47 KB) -> 3 blocks/CU (R10 measured 1 block/CU, 11.6% occupancy).
// ---------------------------------------------------------------------------
__global__ __launch_bounds__(256, 3) void g134(
        const float* __restrict__ feat0, const int* __restrict__ bidx,
        const float* __restrict__ aggws,
        const bf16x8* __restrict__ gW1f, const bf16x8* __restrict__ gW2f,
        const bf16x8* __restrict__ gWtH, const bf16x8* __restrict__ gWtL,
        const bf16x8* __restrict__ gO1H, const bf16x8* __restrict__ gO1L,
        const float* __restrict__ w0b1, const float* __restrict__ w0b2,
        const float* __restrict__ omb1, const float* __restrict__ om2v,
        const float* __restrict__ omb2,
        float* __restrict__ out) {
    __shared__ __align__(16) char poolS[45056];
    __shared__ float sB1w0[128], sB2w0[32], sB1om[128], sOm2[128];

    const int t = threadIdx.x;
    const int l = t & 63, w = t >> 6;
    const int c = l & 15, g = l >> 4;
    const int tile = blockIdx.x;
    const int li = tile >> 4;
    const int o0 = (tile & 15) * 128;
    const int bi = bidx[li];

    if (t < 128) { sB1w0[t] = w0b1[t]; sB1om[t] = omb1[t]; sOm2[t] = om2v[t]; }
    if (t < 32) sB2w0[t] = w0b2[t];
    __syncthreads();

    // ---- G1 ----
    const float* f0b = feat0 + ((long long)bi * O_ + o0) * FIN;
    char* Sw = poolS + w * 11264;
    f32x4 fo[2][2];
    {
        f32x4 acc1[2][8];
        #pragma unroll
        for (int rf = 0; rf < 2; ++rf)
            #pragma unroll
            for (int nf = 0; nf < 8; ++nf) acc1[rf][nf] = (f32x4){0.f, 0.f, 0.f, 0.f};
        #pragma unroll
        for (int rf = 0; rf < 2; ++rf) {
            #pragma unroll
            for (int ks = 0; ks < 2; ++ks) {
                const float* ap = f0b + (w * 32 + rf * 16 + c) * FIN + ks * 32 + g * 8;
                float4 x0 = *(const float4*)ap;
                float4 x1 = *(const float4*)(ap + 4);
                bf16x8 a;
                a[0] = (short)f2b(x0.x); a[1] = (short)f2b(x0.y);
                a[2] = (short)f2b(x0.z); a[3] = (short)f2b(x0.w);
                a[4] = (short)f2b(x1.x); a[5] = (short)f2b(x1.y);
                a[6] = (short)f2b(x1.z); a[7] = (short)f2b(x1.w);
                #pragma unroll
                for (int nf = 0; nf < 8; ++nf)
                    acc1[rf][nf] = __builtin_amdgcn_mfma_f32_16x16x32_bf16(
                        a, gW1f[(nf * 2 + ks) * 64 + l], acc1[rf][nf], 0, 0, 0);
            }
        }
        #pragma unroll
        for (int rf = 0; rf < 2; ++rf)
            #pragma unroll
            for (int nf = 0; nf < 8; ++nf)
                #pragma unroll
                for (int reg = 0; reg < 4; ++reg) {
                    int row = rf * 16 + g * 4 + reg;
                    float hv = acc1[rf][nf][reg] + sB1w0[nf * 16 + c];
                    *(unsigned short*)(Sw + row * 272 + (nf * 16 + c) * 2) =
                        f2b(elu_f(hv));
                }
        #pragma unroll
        for (int rf = 0; rf < 2; ++rf)
            #pragma unroll
            for (int nf2 = 0; nf2 < 2; ++nf2) fo[rf][nf2] = (f32x4){0.f, 0.f, 0.f, 0.f};
        #pragma unroll
        for (int rf = 0; rf < 2; ++rf)
            #pragma unroll
            for (int ks = 0; ks < 4; ++ks) {
                bf16x8 a = *(const bf16x8*)(Sw + (rf * 16 + c) * 272 + ks * 64 + g * 16);
                #pragma unroll
                for (int nf2 = 0; nf2 < 2; ++nf2)
                    fo[rf][nf2] = __builtin_amdgcn_mfma_f32_16x16x32_bf16(
                        a, gW2f[(nf2 * 4 + ks) * 64 + l], fo[rf][nf2], 0, 0, 0);
            }
    }

    // ---- G3/G4 + epilogue ----
    char* tyH = Sw + 4608;      // [16][208B]
    char* tyL = Sw + 7936;
    const float ob2 = omb2[0];
    const long long aggbase = (long long)tile * 128 + w * 32;
    const long long orow0 = (long long)li * O_ + o0 + w * 32;

    #pragma unroll
    for (int rf = 0; rf < 2; ++rf) {
        f32x4 ty[6];
        #pragma unroll
        for (int nf = 0; nf < 6; ++nf) ty[nf] = (f32x4){0.f, 0.f, 0.f, 0.f};
        #pragma unroll
        for (int ks = 0; ks < 2; ++ks) {
            const float* ag = aggws + (aggbase + rf * 16 + c) * 64 + ks * 32 + g * 8;
            float4 x0 = *(const float4*)ag;
            float4 x1 = *(const float4*)(ag + 4);
            bf16x8 aH, aL;
            short h, lo;
            splitw(x0.x, h, lo); aH[0] = h; aL[0] = lo;
            splitw(x0.y, h, lo); aH[1] = h; aL[1] = lo;
            splitw(x0.z, h, lo); aH[2] = h; aL[2] = lo;
            splitw(x0.w, h, lo); aH[3] = h; aL[3] = lo;
            splitw(x1.x, h, lo); aH[4] = h; aL[4] = lo;
            splitw(x1.y, h, lo); aH[5] = h; aL[5] = lo;
            splitw(x1.z, h, lo); aH[6] = h; aL[6] = lo;
            splitw(x1.w, h, lo); aH[7] = h; aL[7] = lo;
            #pragma unroll
            for (int nf = 0; nf < 6; ++nf) {
                bf16x8 bH = gWtH[(nf * 2 + ks) * 64 + l];
                bf16x8 bL = gWtL[(nf * 2 + ks) * 64 + l];
                ty[nf] = __builtin_amdgcn_mfma_f32_16x16x32_bf16(aH, bH, ty[nf], 0, 0, 0);
                ty[nf] = __builtin_amdgcn_mfma_f32_16x16x32_bf16(aL, bH, ty[nf], 0, 0, 0);
                ty[nf] = __builtin_amdgcn_mfma_f32_16x16x32_bf16(aH, bL, ty[nf], 0, 0, 0);
            }
        }
        #pragma unroll
        for (int nf = 0; nf < 6; ++nf)
            #pragma unroll
            for (int reg = 0; reg < 4; ++reg) {
                int row = g * 4 + reg;
                float vv = ty[nf][reg];
                short h, lo; splitw(vv, h, lo);
                *(short*)(tyH + row * 208 + (nf * 16 + c) * 2) = h;
                *(short*)(tyL + row * 208 + (nf * 16 + c) * 2) = lo;
            }
        f32x4 h2[8];
        #pragma unroll
        for (int nf = 0; nf < 8; ++nf) h2[nf] = (f32x4){0.f, 0.f, 0.f, 0.f};
        #pragma unroll
        for (int ks = 0; ks < 3; ++ks) {
            bf16x8 aH = *(const bf16x8*)(tyH + c * 208 + ks * 64 + g * 16);
            bf16x8 aL = *(const bf16x8*)(tyL + c * 208 + ks * 64 + g * 16);
            #pragma unroll
            for (int nf = 0; nf < 8; ++nf) {
                bf16x8 bH = gO1H[(nf * 3 + ks) * 64 + l];
                bf16x8 bL = gO1L[(nf * 3 + ks) * 64 + l];
                h2[nf] = __builtin_amdgcn_mfma_f32_16x16x32_bf16(aH, bH, h2[nf], 0, 0, 0);
                h2[nf] = __builtin_amdgcn_mfma_f32_16x16x32_bf16(aL, bH, h2[nf], 0, 0, 0);
                h2[nf] = __builtin_amdgcn_mfma_f32_16x16x32_bf16(aH, bL, h2[nf], 0, 0, 0);
            }
        }
        float p[4] = {0.f, 0.f, 0.f, 0.f};
        #pragma unroll
        for (int nf = 0; nf < 8; ++nf) {
            float o2 = sOm2[nf * 16 + c];
            float bb = sB1om[nf * 16 + c];
            #pragma unroll
            for (int reg = 0; reg < 4; ++reg)
                p[reg] += elu_f(h2[nf][reg] + bb) * o2;
        }
        #pragma unroll
        for (int reg = 0; reg < 4; ++reg) {
            #pragma unroll
            for (int off = 1; off < 16; off <<= 1)
                p[reg] += __shfl_xor(p[reg], off, 64);
            p[reg] += ob2;
        }
        #pragma unroll
        for (int nf2 = 0; nf2 < 2; ++nf2) {
            float b2v = sB2w0[nf2 * 16 + c];
            #pragma unroll
            for (int reg = 0; reg < 4; ++reg) {
                long long orow = orow0 + rf * 16 + g * 4 + reg;
                float val = fo[rf][nf2][reg] + b2v + p[reg];
                val = val >= 0.f ? val : 0.2f * val;
                out[orow * DOUT + nf2 * 16 + c] = val;
            }
        }
    }
}

// ---------------------------------------------------------------------------
extern "C" void kernel_launch(void* const* d_in, const int* in_sizes, int n_in,
                              void* d_out, int out_size, void* d_ws, size_t ws_size,
                              hipStream_t stream) {
    const float* feat0 = (const float*)d_in[0];
    const float* feat1 = (const float*)d_in[1];
    const float* feat2 = (const float*)d_in[2];
    const int*   adj   = (const int*)d_in[3];
    const int*   bidx  = (const int*)d_in[4];
    const float* w0_w1 = (const float*)d_in[5];
    const float* w0_b1 = (const float*)d_in[6];
    const float* w0_w2 = (const float*)d_in[7];
    const float* w0_b2 = (const float*)d_in[8];
    const float* v     = (const float*)d_in[9];
    const float* coeff = (const float*)d_in[10];
    const float* e_w1  = (const float*)d_in[11];
    const float* e_b1  = (const float*)d_in[12];
    const float* e_w2  = (const float*)d_in[13];
    const float* e_b2  = (const float*)d_in[14];
    const float* om_w1 = (const float*)d_in[15];
    const float* om_b1 = (const float*)d_in[16];
    const float* om_w2 = (const float*)d_in[17];
    const float* om_b2 = (const float*)d_in[18];
    float* out = (float*)d_out;
    char*  wsb = (char*)d_ws;

    const int bsel = in_sizes[4];              // 32

    float*  ws_scal = (float*)wsb;                    // 64 B
    bf16x8* ws_w1f  = (bf16x8*)(wsb + 4096);          // 16 KB
    bf16x8* ws_w2f  = (bf16x8*)(wsb + 20480);         // 8 KB
    bf16x8* ws_wth  = (bf16x8*)(wsb + 28672);         // 12 KB
    bf16x8* ws_wtl  = (bf16x8*)(wsb + 40960);         // 12 KB
    bf16x8* ws_o1h  = (bf16x8*)(wsb + 53248);         // 24 KB
    bf16x8* ws_o1l  = (bf16x8*)(wsb + 77824);         // 24 KB
    bf16x8* ws_hf   = (bf16x8*)(wsb + 131072);        // 2 MB
    float*  ws_agg  = (float*)(wsb + 131072 + 2097152); // 16.8 MB

    kprep<<<15, 256, 0, stream>>>(e_w1, e_b1, e_w2, e_b2, coeff, v,
                                  w0_w1, w0_w2, om_w1,
                                  ws_scal, ws_w1f, ws_w2f, ws_wth, ws_wtl,
                                  ws_o1h, ws_o1l);
    khf<<<bsel * 4, 256, 0, stream>>>(feat1, bidx, ws_hf);
    g2<<<bsel * 32, 256, 0, stream>>>(feat2, adj, bidx, ws_scal, ws_hf, ws_agg);
    g134<<<bsel * 16, 256, 0, stream>>>(feat0, bidx, ws_agg,
                                        ws_w1f, ws_w2f, ws_wth, ws_wtl,
                                        ws_o1h, ws_o1l,
                                        w0_b1, w0_b2, om_b1, om_w2, om_b2, out);
}

// Round 13
// 65.486 us; speedup vs baseline: 8.8257x; 1.3623x over previous
//
#include <hip/hip_runtime.h>

#define O_ 2048
#define M_ 512
#define FIN 64
#define FMAS 64
#define DOUT 32
#define H_ 128
#define TD 96
#define NB_ 3

typedef __attribute__((ext_vector_type(4))) float f32x4;
typedef __attribute__((ext_vector_type(8))) short bf16x8;

__device__ __forceinline__ float elu_f(float x) {
    return x > 0.f ? x : (__expf(x) - 1.f);
}
__device__ __forceinline__ unsigned short f2b(float x) {
    union { float f; unsigned u; } uu; uu.f = x;
    unsigned r = uu.u + 0x7fffu + ((uu.u >> 16) & 1u);
    return (unsigned short)(r >> 16);
}
__device__ __forceinline__ float b2f(unsigned short s) {
    union { float f; unsigned u; } uu; uu.u = ((unsigned)s) << 16;
    return uu.f;
}
__device__ __forceinline__ void splitw(float x, short& h, short& lo) {
    unsigned u = __float_as_uint(x);
    unsigned short hi = (unsigned short)(u >> 16);
    float rem = x - b2f(hi);
    h = (short)hi;
    lo = (short)(unsigned short)(__float_as_uint(rem) >> 16);
}

// ---------------------------------------------------------------------------
// PREP (143 blocks): blocks 0..14 = weight fragment tables + scalars;
// blocks 15..142 = per-li bf16 H fragment tables (khf).
// ---------------------------------------------------------------------------
__global__ __launch_bounds__(256) void prep(
        const float* __restrict__ e_w1, const float* __restrict__ e_b1,
        const float* __restrict__ e_w2, const float* __restrict__ e_b2,
        const float* __restrict__ coeff, const float* __restrict__ v,
        const float* __restrict__ w0w1, const float* __restrict__ w0w2,
        const float* __restrict__ om1, const float* __restrict__ hmas,
        const int* __restrict__ bidx,
        float* __restrict__ ws_scal,
        bf16x8* __restrict__ w1f, bf16x8* __restrict__ w2f,
        bf16x8* __restrict__ wth, bf16x8* __restrict__ wtl,
        bf16x8* __restrict__ o1h, bf16x8* __restrict__ o1l,
        bf16x8* __restrict__ hf) {
    const int t = threadIdx.x;
    if (blockIdx.x < 15) {
        __shared__ float r1[128], r2[128];
        if (t < 128) { r1[t] = e_w1[t] * e_w2[t]; r2[t] = e_b1[t] * e_w2[t]; }
        __syncthreads();
        for (int s = 64; s > 0; s >>= 1) {
            if (t < s) { r1[t] += r1[t + s]; r2[t] += r2[t + s]; }
            __syncthreads();
        }
        if (blockIdx.x == 0 && t == 0) {
            ws_scal[0] = r1[0];
            ws_scal[1] = r2[0] + e_b2[0];
        }
        const int e = blockIdx.x * 256 + t;       // [0, 3840)
        const int le = e & 63, cc = le & 15, gg = le >> 4;
        if (e < 1024) {
            int nf = e >> 7, ks = (e >> 6) & 1;
            bf16x8 vv;
            #pragma unroll
            for (int j = 0; j < 8; ++j)
                vv[j] = (short)f2b(w0w1[(ks * 32 + gg * 8 + j) * H_ + nf * 16 + cc]);
            w1f[e] = vv;
        } else if (e < 1536) {
            int e2 = e - 1024;
            int nf = e2 >> 8, ks = (e2 >> 6) & 3;
            bf16x8 vv;
            #pragma unroll
            for (int j = 0; j < 8; ++j)
                vv[j] = (short)f2b(w0w2[(ks * 32 + gg * 8 + j) * DOUT + nf * 16 + cc]);
            w2f[e2] = vv;
        } else if (e < 2304) {
            int e3 = e - 1536;
            int nf = e3 >> 7, ks = (e3 >> 6) & 1;
            bf16x8 vh, vl;
            #pragma unroll
            for (int j = 0; j < 8; ++j) {
                int row = ks * 32 + gg * 8 + j;
                int col = nf * 16 + cc;
                int tt = col >> 5, ee = col & 31;
                float s = 0.f;
                #pragma unroll
                for (int nb = 0; nb < NB_; ++nb)
                    s += coeff[tt * NB_ + nb] * v[(nb * FMAS + row) * DOUT + ee];
                short h, lo; splitw(s, h, lo);
                vh[j] = h; vl[j] = lo;
            }
            wth[e3] = vh; wtl[e3] = vl;
        } else if (e < 3840) {
            int e4 = e - 2304;
            int nf = e4 / 192, r = e4 % 192, ks = r >> 6;
            bf16x8 vh, vl;
            #pragma unroll
            for (int j = 0; j < 8; ++j) {
                float vv = om1[(ks * 32 + gg * 8 + j) * H_ + nf * 16 + cc];
                short h, lo; splitw(vv, h, lo);
                vh[j] = h; vl[j] = lo;
            }
            o1h[e4] = vh; o1l[e4] = vl;
        }
    } else {
        const int b2 = blockIdx.x - 15;
        const int li = b2 >> 2;
        const int part = b2 & 3;
        const int bi = bidx[li];
        const float* hb = hmas + (long long)bi * M_ * FMAS;
        bf16x8* dst = hf + li * 4096;
        #pragma unroll
        for (int j4 = 0; j4 < 4; ++j4) {
            int e = part * 1024 + j4 * 256 + t;
            int ft = e >> 10, ks = (e >> 6) & 15, le = e & 63;
            int cc = le & 15, gg = le >> 4;
            const float* src = hb + (ks * 32 + gg * 8) * FMAS + ft * 16 + cc;
            bf16x8 vv;
            #pragma unroll
            for (int j = 0; j < 8; ++j) vv[j] = (short)f2b(src[j * FMAS]);
            dst[e] = vv;
        }
    }
}

// ---------------------------------------------------------------------------
// GFUSED: per wave = 16 complete output rows; no barriers anywhere.
// Phase A (stream): agg = (mask*(ke*feat2+ce)) @ H  -- R9 LDS-staged A-tile,
//   XOR-swizzled, 2-deep register prefetch; acc stays in registers.
// Phase B (epilogue, per-wave): G1 feat_opt MLP -> G3 typed -> G4 om-MLP
//   -> leaky(fo + mas_w) -> out.  Scratch reuses the wave's 8KB stream tile
//   (sequential aliasing; DS ops are in-order per wave).
// Weight fragments from L2-hot ws tables. Epilogue compute from sibling
// waves fills the stream phase's HBM-latency bubbles.
// ---------------------------------------------------------------------------
__global__ __launch_bounds__(256, 3) void gfused(
        const float* __restrict__ feat2, const int* __restrict__ adj,
        const float* __restrict__ feat0, const int* __restrict__ bidx,
        const float* __restrict__ scal, const bf16x8* __restrict__ hf,
        const bf16x8* __restrict__ gW1f, const bf16x8* __restrict__ gW2f,
        const bf16x8* __restrict__ gWtH, const bf16x8* __restrict__ gWtL,
        const bf16x8* __restrict__ gO1H, const bf16x8* __restrict__ gO1L,
        const float* __restrict__ w0b1, const float* __restrict__ w0b2,
        const float* __restrict__ omb1, const float* __restrict__ om2v,
        const float* __restrict__ omb2,
        float* __restrict__ out) {
    __shared__ char tile[32768];              // 8 KB per wave
    const int t = threadIdx.x;
    const int w = t >> 6, l = t & 63;
    const int c = l & 15, g = l >> 4;
    const int r16 = blockIdx.x * 4 + w;       // 16-row unit id
    const int li = r16 >> 7;
    const int bi = bidx[li];
    float ke = scal[0], ce = scal[1];
    asm volatile("" : "+v"(ke), "+v"(ce));    // VGPR-pin (constant-bus limit)
    const long long rowg = (long long)bi * O_ + ((r16 & 127) * 16);
    const float* f2base = feat2 + rowg * M_;
    const int*   adb    = adj   + rowg * M_;
    const bf16x8* hfb = hf + li * 4096;
    char* wbase = tile + w * 8192;

    const int rl = l >> 4, q = l & 15;
    const float* gF0 = f2base + (0 * 4 + rl) * 512 + q * 4;
    const float* gF1 = f2base + (1 * 4 + rl) * 512 + q * 4;
    const float* gF2 = f2base + (2 * 4 + rl) * 512 + q * 4;
    const float* gF3 = f2base + (3 * 4 + rl) * 512 + q * 4;
    const int* gA0 = adb + (0 * 4 + rl) * 512 + q * 4;
    const int* gA1 = adb + (1 * 4 + rl) * 512 + q * 4;
    const int* gA2 = adb + (2 * 4 + rl) * 512 + q * 4;
    const int* gA3 = adb + (3 * 4 + rl) * 512 + q * 4;
    char* wp0 = wbase + (((0 * 4 + rl) * 16 + (q ^ ((0 * 4 + rl) & 7))) * 16);
    char* wp1 = wbase + (((1 * 4 + rl) * 16 + (q ^ ((1 * 4 + rl) & 7))) * 16);
    char* wp2 = wbase + (((2 * 4 + rl) * 16 + (q ^ ((2 * 4 + rl) & 7))) * 16);
    char* wp3 = wbase + (((3 * 4 + rl) * 16 + (q ^ ((3 * 4 + rl) & 7))) * 16);
    const int s7 = c & 7;
    const char* rd0 = wbase + ((c * 16 + ((g * 2 + 0) ^ s7)) * 16);
    const char* rd1 = wbase + ((c * 16 + ((g * 2 + 1) ^ s7)) * 16);

    f32x4 acc0 = {0.f, 0.f, 0.f, 0.f}, acc1 = {0.f, 0.f, 0.f, 0.f};
    f32x4 acc2 = {0.f, 0.f, 0.f, 0.f}, acc3 = {0.f, 0.f, 0.f, 0.f};

    float4 fA0, fA1, fA2, fA3, fB0, fB1, fB2, fB3;
    int4   aA0, aA1, aA2, aA3, aB0, aB1, aB2, aB3;

#define G2LOADG(ch, F0, F1, F2, F3, A0, A1, A2, A3) {                   \
    F0 = *(const float4*)(gF0 + (ch) * 64);                             \
    F1 = *(const float4*)(gF1 + (ch) * 64);                             \
    F2 = *(const float4*)(gF2 + (ch) * 64);                             \
    F3 = *(const float4*)(gF3 + (ch) * 64);                             \
    A0 = *(const int4*)(gA0 + (ch) * 64);                               \
    A1 = *(const int4*)(gA1 + (ch) * 64);                               \
    A2 = *(const int4*)(gA2 + (ch) * 64);                               \
    A3 = *(const int4*)(gA3 + (ch) * 64); }

#define G2STORE_LDS(F0, F1, F2, F3, A0, A1, A2, A3) {                   \
    *(float4*)wp0 = F0; *(float4*)wp1 = F1;                             \
    *(float4*)wp2 = F2; *(float4*)wp3 = F3;                             \
    *(int4*)(wp0 + 4096) = A0; *(int4*)(wp1 + 4096) = A1;               \
    *(int4*)(wp2 + 4096) = A2; *(int4*)(wp3 + 4096) = A3; }

#define G2CV4(e4, m4, ah, al_, o) {                                     \
    short h_, l_;                                                       \
    splitw((m4.x == 1) ? fmaf(e4.x, ke, ce) : 0.f, h_, l_);             \
    ah[o + 0] = h_; al_[o + 0] = l_;                                    \
    splitw((m4.y == 1) ? fmaf(e4.y, ke, ce) : 0.f, h_, l_);             \
    ah[o + 1] = h_; al_[o + 1] = l_;                                    \
    splitw((m4.z == 1) ? fmaf(e4.z, ke, ce) : 0.f, h_, l_);             \
    ah[o + 2] = h_; al_[o + 2] = l_;                                    \
    splitw((m4.w == 1) ? fmaf(e4.w, ke, ce) : 0.f, h_, l_);             \
    ah[o + 3] = h_; al_[o + 3] = l_; }

#define G2KS(ksg, off) {                                                \
    float4 e0 = *(const float4*)(rd0 + (off));                          \
    float4 e1 = *(const float4*)(rd1 + (off));                          \
    int4   m0 = *(const int4*)(rd0 + 4096 + (off));                     \
    int4   m1 = *(const int4*)(rd1 + 4096 + (off));                     \
    bf16x8 bb0 = hfb[(0 * 16 + (ksg)) * 64 + l];                        \
    bf16x8 bb1 = hfb[(1 * 16 + (ksg)) * 64 + l];                        \
    bf16x8 bb2 = hfb[(2 * 16 + (ksg)) * 64 + l];                        \
    bf16x8 bb3 = hfb[(3 * 16 + (ksg)) * 64 + l];                        \
    bf16x8 ah, al_;                                                     \
    G2CV4(e0, m0, ah, al_, 0);                                          \
    G2CV4(e1, m1, ah, al_, 4);                                          \
    acc0 = __builtin_amdgcn_mfma_f32_16x16x32_bf16(ah, bb0, acc0, 0, 0, 0); \
    acc0 = __builtin_amdgcn_mfma_f32_16x16x32_bf16(al_, bb0, acc0, 0, 0, 0); \
    acc1 = __builtin_amdgcn_mfma_f32_16x16x32_bf16(ah, bb1, acc1, 0, 0, 0); \
    acc1 = __builtin_amdgcn_mfma_f32_16x16x32_bf16(al_, bb1, acc1, 0, 0, 0); \
    acc2 = __builtin_amdgcn_mfma_f32_16x16x32_bf16(ah, bb2, acc2, 0, 0, 0); \
    acc2 = __builtin_amdgcn_mfma_f32_16x16x32_bf16(al_, bb2, acc2, 0, 0, 0); \
    acc3 = __builtin_amdgcn_mfma_f32_16x16x32_bf16(ah, bb3, acc3, 0, 0, 0); \
    acc3 = __builtin_amdgcn_mfma_f32_16x16x32_bf16(al_, bb3, acc3, 0, 0, 0); }

    // ---- Phase A: stream loop, 2-deep register prefetch ----
    G2LOADG(0, fA0, fA1, fA2, fA3, aA0, aA1, aA2, aA3);
    G2LOADG(1, fB0, fB1, fB2, fB3, aB0, aB1, aB2, aB3);
    #pragma unroll
    for (int ip = 0; ip < 4; ++ip) {
        G2STORE_LDS(fA0, fA1, fA2, fA3, aA0, aA1, aA2, aA3);
        if (ip < 3) G2LOADG(2 * ip + 2, fA0, fA1, fA2, fA3, aA0, aA1, aA2, aA3);
        G2KS(4 * ip + 0, 0);
        G2KS(4 * ip + 1, 128);
        G2STORE_LDS(fB0, fB1, fB2, fB3, aB0, aB1, aB2, aB3);
        if (ip < 3) G2LOADG(2 * ip + 3, fB0, fB1, fB2, fB3, aB0, aB1, aB2, aB3);
        G2KS(4 * ip + 2, 0);
        G2KS(4 * ip + 3, 128);
    }

    // ---- Phase B: per-wave epilogue (scratch = wave tile, seq. aliasing) ----
    char* Sw = wbase;
    const long long outbase = (long long)li * O_ + ((r16 & 127) * 16);

    // G1: feat_opt = elu(feat0@W1+b1)@W2
    f32x4 fo[2];
    {
        const float* f0b = feat0 + rowg * FIN;
        f32x4 h1[8];
        #pragma unroll
        for (int nf = 0; nf < 8; ++nf) h1[nf] = (f32x4){0.f, 0.f, 0.f, 0.f};
        #pragma unroll
        for (int ks = 0; ks < 2; ++ks) {
            const float* ap = f0b + c * FIN + ks * 32 + g * 8;
            float4 x0 = *(const float4*)ap;
            float4 x1 = *(const float4*)(ap + 4);
            bf16x8 a;
            a[0] = (short)f2b(x0.x); a[1] = (short)f2b(x0.y);
            a[2] = (short)f2b(x0.z); a[3] = (short)f2b(x0.w);
            a[4] = (short)f2b(x1.x); a[5] = (short)f2b(x1.y);
            a[6] = (short)f2b(x1.z); a[7] = (short)f2b(x1.w);
            #pragma unroll
            for (int nf = 0; nf < 8; ++nf)
                h1[nf] = __builtin_amdgcn_mfma_f32_16x16x32_bf16(
                    a, gW1f[(nf * 2 + ks) * 64 + l], h1[nf], 0, 0, 0);
        }
        #pragma unroll
        for (int nf = 0; nf < 8; ++nf) {
            float bb = w0b1[nf * 16 + c];
            #pragma unroll
            for (int reg = 0; reg < 4; ++reg) {
                int row = g * 4 + reg;
                *(unsigned short*)(Sw + row * 272 + (nf * 16 + c) * 2) =
                    f2b(elu_f(h1[nf][reg] + bb));
            }
        }
        fo[0] = (f32x4){0.f, 0.f, 0.f, 0.f};
        fo[1] = (f32x4){0.f, 0.f, 0.f, 0.f};
        #pragma unroll
        for (int ks = 0; ks < 4; ++ks) {
            bf16x8 a = *(const bf16x8*)(Sw + c * 272 + ks * 64 + g * 16);
            #pragma unroll
            for (int nf2 = 0; nf2 < 2; ++nf2)
                fo[nf2] = __builtin_amdgcn_mfma_f32_16x16x32_bf16(
                    a, gW2f[(nf2 * 4 + ks) * 64 + l], fo[nf2], 0, 0, 0);
        }
    }

    // G3: typed = agg @ Wt  (acc -> hi/lo scratch transpose -> MFMA)
    f32x4 ty[6];
    {
        char* aggH = Sw;
        char* aggL = Sw + 2304;
        #pragma unroll
        for (int reg = 0; reg < 4; ++reg) {
            int row = g * 4 + reg;
            short h, lo;
            splitw(acc0[reg], h, lo);
            *(short*)(aggH + row * 144 + (0 * 16 + c) * 2) = h;
            *(short*)(aggL + row * 144 + (0 * 16 + c) * 2) = lo;
            splitw(acc1[reg], h, lo);
            *(short*)(aggH + row * 144 + (1 * 16 + c) * 2) = h;
            *(short*)(aggL + row * 144 + (1 * 16 + c) * 2) = lo;
            splitw(acc2[reg], h, lo);
            *(short*)(aggH + row * 144 + (2 * 16 + c) * 2) = h;
            *(short*)(aggL + row * 144 + (2 * 16 + c) * 2) = lo;
            splitw(acc3[reg], h, lo);
            *(short*)(aggH + row * 144 + (3 * 16 + c) * 2) = h;
            *(short*)(aggL + row * 144 + (3 * 16 + c) * 2) = lo;
        }
        #pragma unroll
        for (int nf = 0; nf < 6; ++nf) ty[nf] = (f32x4){0.f, 0.f, 0.f, 0.f};
        #pragma unroll
        for (int ks = 0; ks < 2; ++ks) {
            bf16x8 aH = *(const bf16x8*)(aggH + c * 144 + ks * 64 + g * 16);
            bf16x8 aL = *(const bf16x8*)(aggL + c * 144 + ks * 64 + g * 16);
            #pragma unroll
            for (int nf = 0; nf < 6; ++nf) {
                bf16x8 bH = gWtH[(nf * 2 + ks) * 64 + l];
                bf16x8 bL = gWtL[(nf * 2 + ks) * 64 + l];
                ty[nf] = __builtin_amdgcn_mfma_f32_16x16x32_bf16(aH, bH, ty[nf], 0, 0, 0);
                ty[nf] = __builtin_amdgcn_mfma_f32_16x16x32_bf16(aL, bH, ty[nf], 0, 0, 0);
                ty[nf] = __builtin_amdgcn_mfma_f32_16x16x32_bf16(aH, bL, ty[nf], 0, 0, 0);
            }
        }
    }

    // G4: mas_w = elu(typed@om1+b1)@om2 + b2  (ty -> hi/lo scratch -> MFMA)
    float p[4] = {0.f, 0.f, 0.f, 0.f};
    {
        char* tyH = Sw;
        char* tyL = Sw + 3328;
        #pragma unroll
        for (int nf = 0; nf < 6; ++nf)
            #pragma unroll
            for (int reg = 0; reg < 4; ++reg) {
                int row = g * 4 + reg;
                short h, lo; splitw(ty[nf][reg], h, lo);
                *(short*)(tyH + row * 208 + (nf * 16 + c) * 2) = h;
                *(short*)(tyL + row * 208 + (nf * 16 + c) * 2) = lo;
            }
        f32x4 h2[8];
        #pragma unroll
        for (int nf = 0; nf < 8; ++nf) h2[nf] = (f32x4){0.f, 0.f, 0.f, 0.f};
        #pragma unroll
        for (int ks = 0; ks < 3; ++ks) {
            bf16x8 aH = *(const bf16x8*)(tyH + c * 208 + ks * 64 + g * 16);
            bf16x8 aL = *(const bf16x8*)(tyL + c * 208 + ks * 64 + g * 16);
            #pragma unroll
            for (int nf = 0; nf < 8; ++nf) {
                bf16x8 bH = gO1H[(nf * 3 + ks) * 64 + l];
                bf16x8 bL = gO1L[(nf * 3 + ks) * 64 + l];
                h2[nf] = __builtin_amdgcn_mfma_f32_16x16x32_bf16(aH, bH, h2[nf], 0, 0, 0);
                h2[nf] = __builtin_amdgcn_mfma_f32_16x16x32_bf16(aL, bH, h2[nf], 0, 0, 0);
                h2[nf] = __builtin_amdgcn_mfma_f32_16x16x32_bf16(aH, bL, h2[nf], 0, 0, 0);
            }
        }
        #pragma unroll
        for (int nf = 0; nf < 8; ++nf) {
            float o2 = om2v[nf * 16 + c];
            float bb = omb1[nf * 16 + c];
            #pragma unroll
            for (int reg = 0; reg < 4; ++reg)
                p[reg] += elu_f(h2[nf][reg] + bb) * o2;
        }
        const float ob2 = omb2[0];
        #pragma unroll
        for (int reg = 0; reg < 4; ++reg) {
            #pragma unroll
            for (int off = 1; off < 16; off <<= 1)
                p[reg] += __shfl_xor(p[reg], off, 64);
            p[reg] += ob2;
        }
    }

    // epilogue: out = leaky_relu(feat_opt + b2 + mas_w)
    #pragma unroll
    for (int nf2 = 0; nf2 < 2; ++nf2) {
        float b2v = w0b2[nf2 * 16 + c];
        #pragma unroll
        for (int reg = 0; reg < 4; ++reg) {
            long long orow = outbase + g * 4 + reg;
            float val = fo[nf2][reg] + b2v + p[reg];
            val = val >= 0.f ? val : 0.2f * val;
            out[orow * DOUT + nf2 * 16 + c] = val;
        }
    }
#undef G2LOADG
#undef G2STORE_LDS
#undef G2CV4
#undef G2KS
}

// ---------------------------------------------------------------------------
extern "C" void kernel_launch(void* const* d_in, const int* in_sizes, int n_in,
                              void* d_out, int out_size, void* d_ws, size_t ws_size,
                              hipStream_t stream) {
    const float* feat0 = (const float*)d_in[0];
    const float* feat1 = (const float*)d_in[1];
    const float* feat2 = (const float*)d_in[2];
    const int*   adj   = (const int*)d_in[3];
    const int*   bidx  = (const int*)d_in[4];
    const float* w0_w1 = (const float*)d_in[5];
    const float* w0_b1 = (const float*)d_in[6];
    const float* w0_w2 = (const float*)d_in[7];
    const float* w0_b2 = (const float*)d_in[8];
    const float* v     = (const float*)d_in[9];
    const float* coeff = (const float*)d_in[10];
    const float* e_w1  = (const float*)d_in[11];
    const float* e_b1  = (const float*)d_in[12];
    const float* e_w2  = (const float*)d_in[13];
    const float* e_b2  = (const float*)d_in[14];
    const float* om_w1 = (const float*)d_in[15];
    const float* om_b1 = (const float*)d_in[16];
    const float* om_w2 = (const float*)d_in[17];
    const float* om_b2 = (const float*)d_in[18];
    float* out = (float*)d_out;
    char*  wsb = (char*)d_ws;

    const int bsel = in_sizes[4];              // 32

    float*  ws_scal = (float*)wsb;                    // 64 B
    bf16x8* ws_w1f  = (bf16x8*)(wsb + 4096);          // 16 KB
    bf16x8* ws_w2f  = (bf16x8*)(wsb + 20480);         // 8 KB
    bf16x8* ws_wth  = (bf16x8*)(wsb + 28672);         // 12 KB
    bf16x8* ws_wtl  = (bf16x8*)(wsb + 40960);         // 12 KB
    bf16x8* ws_o1h  = (bf16x8*)(wsb + 53248);         // 24 KB
    bf16x8* ws_o1l  = (bf16x8*)(wsb + 77824);         // 24 KB
    bf16x8* ws_hf   = (bf16x8*)(wsb + 131072);        // 2 MB

    prep<<<15 + bsel * 4, 256, 0, stream>>>(e_w1, e_b1, e_w2, e_b2, coeff, v,
                                            w0_w1, w0_w2, om_w1, feat1, bidx,
                                            ws_scal, ws_w1f, ws_w2f,
                                            ws_wth, ws_wtl, ws_o1h, ws_o1l,
                                            ws_hf);
    gfused<<<bsel * 32, 256, 0, stream>>>(feat2, adj, feat0, bidx,
                                          ws_scal, ws_hf,
                                          ws_w1f, ws_w2f, ws_wth, ws_wtl,
                                          ws_o1h, ws_o1l,
                                          w0_b1, w0_b2, om_b1, om_w2, om_b2,
                                          out);
}